// Round 2
// baseline (4669.091 us; speedup 1.0000x reference)
//
#include <hip/hip_runtime.h>
#include <hip/hip_bf16.h>
#include <cstdint>
#include <cstddef>

#define HIDDEN 450
#define ATOM_FDIM 35
#define IN_FDIM 40        // ATOM_FDIM + BOND_FDIM
#define MAX_NB 15
#define N_ATOMS 30000
#define N_BONDS 60000
#define N_MESS 10001
#define N_MOLS 1000
#define DEPTH 4
#define NTOT (N_MESS + N_BONDS)

// ---- storage-type helpers (float or bf16 message buffers) ------------------
__device__ __forceinline__ float ld_val(const float* p) { return *p; }
__device__ __forceinline__ float ld_val(const __hip_bfloat16* p) { return __bfloat162float(*p); }
__device__ __forceinline__ void st_val(float* p, float v) { *p = v; }
__device__ __forceinline__ void st_val(__hip_bfloat16* p, float v) { *p = __float2bfloat16(v); }

// ---- index-width sniffing: int64 arrays have zero high words ---------------
__device__ __forceinline__ bool sniff_is64(const void* g) {
    const int* g32 = (const int*)g;
    return (g32[1] | g32[3] | g32[5] | g32[7]) == 0;
}
__device__ __forceinline__ long long load_idx(const void* g, size_t pos, bool is64) {
    return is64 ? ((const long long*)g)[pos] : (long long)((const int*)g)[pos];
}

// ---------------- GEMM: Out = act([A1|A2] @ [B1|B2]^T [+ bias]) -------------
// A1 fp32 [M x ka1] ld lda1; A2 (storage T) covers cols [ka1,K) ld lda2.
// B1 fp32 [N x kb1] ld ldb1; B2 fp32 covers cols [kb1,K) ld ldb2.
template<typename ST, bool BIAS, bool RELU>
__global__ __launch_bounds__(256)
void gemm_kernel(const float* __restrict__ A1, int lda1, int ka1,
                 const ST* __restrict__ A2, int lda2,
                 const float* __restrict__ B1, int ldb1, int kb1,
                 const float* __restrict__ B2, int ldb2,
                 const float* __restrict__ bias,
                 ST* __restrict__ Out,
                 int M, int N, int K)
{
    __shared__ __align__(16) float As[32][68];
    __shared__ __align__(16) float Bs[32][68];
    const int tid = threadIdx.x;
    const int m0 = blockIdx.x * 64;
    const int n0 = blockIdx.y * 64;
    const int tx = tid & 15;        // 16 -> M dir
    const int ty = tid >> 4;        // 16 -> N dir
    float acc[4][4] = {};

    for (int k0 = 0; k0 < K; k0 += 32) {
        #pragma unroll
        for (int i = 0; i < 8; ++i) {
            int idx = i * 256 + tid;
            int r  = idx >> 5;      // 0..63
            int kk = idx & 31;
            int gk = k0 + kk;
            float av = 0.f, bv = 0.f;
            int gmr = m0 + r;
            if (gmr < M && gk < K) {
                if (gk < ka1) av = A1[(size_t)gmr * lda1 + gk];
                else          av = ld_val(&A2[(size_t)gmr * lda2 + (gk - ka1)]);
            }
            int gnr = n0 + r;
            if (gnr < N && gk < K) {
                if (gk < kb1) bv = B1[(size_t)gnr * ldb1 + gk];
                else          bv = B2[(size_t)gnr * ldb2 + (gk - kb1)];
            }
            As[kk][r] = av;
            Bs[kk][r] = bv;
        }
        __syncthreads();
        #pragma unroll
        for (int kk = 0; kk < 32; ++kk) {
            float4 a4 = *(const float4*)&As[kk][tx * 4];
            float4 b4 = *(const float4*)&Bs[kk][ty * 4];
            float a[4] = {a4.x, a4.y, a4.z, a4.w};
            float b[4] = {b4.x, b4.y, b4.z, b4.w};
            #pragma unroll
            for (int i = 0; i < 4; ++i)
                #pragma unroll
                for (int j = 0; j < 4; ++j)
                    acc[i][j] = fmaf(a[i], b[j], acc[i][j]);
        }
        __syncthreads();
    }

    #pragma unroll
    for (int i = 0; i < 4; ++i) {
        int gmr = m0 + tx * 4 + i;
        if (gmr >= M) continue;
        #pragma unroll
        for (int j = 0; j < 4; ++j) {
            int gnr = n0 + ty * 4 + j;
            if (gnr >= N) continue;
            float v = acc[i][j];
            if (BIAS) v += bias[gnr];
            if (RELU) v = fmaxf(v, 0.f);
            st_val(&Out[(size_t)gmr * N + gnr], v);
        }
    }
}

// -------- gather-sum: out[r] = sum_{nb} message[graph[r][nb]]  (row 450) ----
// message[idx] = idx < N_MESS ? tree[idx] : gmsg[idx - N_MESS]
template<typename ST>
__global__ __launch_bounds__(256)
void gather_sum_kernel(const void* __restrict__ graph, int n_rows,
                       const float* __restrict__ tree,
                       const ST* __restrict__ gmsg,
                       ST* __restrict__ out)
{
    __shared__ bool is64_s;
    if (threadIdx.x == 0) is64_s = sniff_is64(graph);
    __syncthreads();
    const bool is64 = is64_s;

    int w    = (int)((blockIdx.x * 256 + threadIdx.x) >> 6);
    int lane = threadIdx.x & 63;
    if (w >= n_rows) return;

    float acc[8] = {};
    for (int nb = 0; nb < MAX_NB; ++nb) {
        long long idx = load_idx(graph, (size_t)w * MAX_NB + nb, is64);
        if (idx < 0) idx = 0;
        if (idx >= NTOT) idx = NTOT - 1;
        if (idx < N_MESS) {
            const float* row = tree + (size_t)idx * HIDDEN;
            #pragma unroll
            for (int j = 0; j < 8; ++j) {
                int c = lane + 64 * j;
                if (c < HIDDEN) acc[j] += row[c];
            }
        } else {
            const ST* row = gmsg + (size_t)(idx - N_MESS) * HIDDEN;
            #pragma unroll
            for (int j = 0; j < 8; ++j) {
                int c = lane + 64 * j;
                if (c < HIDDEN) acc[j] += ld_val(&row[c]);
            }
        }
    }
    ST* orow = out + (size_t)w * HIDDEN;
    #pragma unroll
    for (int j = 0; j < 8; ++j) {
        int c = lane + 64 * j;
        if (c < HIDDEN) st_val(&orow[c], acc[j]);
    }
}

// -------- zero the stats accumulators ---------------------------------------
__global__ void zero_stats_kernel(float* __restrict__ p)
{
    int i = blockIdx.x * blockDim.x + threadIdx.x;
    if (i < 2 * HIDDEN) p[i] = 0.f;
}

// -------- column stats (sum, sumsq) over h[N_ATOMS][HIDDEN] ----------------
template<typename ST>
__global__ __launch_bounds__(256)
void colstats_kernel(const ST* __restrict__ h,
                     float* __restrict__ sums, float* __restrict__ sumsq)
{
    int t = threadIdx.x;
    int r0 = blockIdx.x * 250;
    float s0 = 0.f, q0 = 0.f, s1 = 0.f, q1 = 0.f;
    bool has1 = t < HIDDEN - 256;
    for (int r = r0; r < r0 + 250; ++r) {
        const ST* row = h + (size_t)r * HIDDEN;
        float v0 = ld_val(&row[t]);
        s0 += v0; q0 += v0 * v0;
        if (has1) {
            float v1 = ld_val(&row[t + 256]);
            s1 += v1; q1 += v1 * v1;
        }
    }
    atomicAdd(&sums[t], s0);
    atomicAdd(&sumsq[t], q0);
    if (has1) {
        atomicAdd(&sums[t + 256], s1);
        atomicAdd(&sumsq[t + 256], q1);
    }
}

__global__ void finalize_stats_kernel(const float* __restrict__ sums,
                                      const float* __restrict__ sumsq,
                                      const float* __restrict__ gamma,
                                      const float* __restrict__ beta,
                                      float* __restrict__ scale,
                                      float* __restrict__ shift)
{
    int c = blockIdx.x * blockDim.x + threadIdx.x;
    if (c >= HIDDEN) return;
    float mean = sums[c] * (1.f / N_ATOMS);
    float var  = sumsq[c] * (1.f / N_ATOMS) - mean * mean;
    float inv  = rsqrtf(var + 1e-5f);
    float sc   = gamma[c] * inv;
    scale[c] = sc;
    shift[c] = beta[c] - mean * sc;
}

// -------- per-mol mean of relu(h*scale + shift) -----------------------------
template<typename ST>
__global__ __launch_bounds__(256)
void pool_kernel(const ST* __restrict__ h, const void* __restrict__ scope,
                 const float* __restrict__ scale, const float* __restrict__ shift,
                 float* __restrict__ out)
{
    int m = blockIdx.x;
    const int* s32 = (const int*)scope;
    // int64 layout: words (1,3) are high words of start0/len0 -> 0.
    // int32 layout: word 1 = len0 (=30 here) != 0.
    bool is64 = (s32[1] == 0 && s32[3] == 0);
    long long start, len, nxt;
    if (is64) {
        const long long* s = (const long long*)scope;
        start = s[2 * m]; len = s[2 * m + 1];
        nxt = (m < N_MOLS - 1) ? s[2 * m + 2] : (long long)N_ATOMS;
    } else {
        start = s32[2 * m]; len = s32[2 * m + 1];
        nxt = (m < N_MOLS - 1) ? (long long)s32[2 * m + 2] : (long long)N_ATOMS;
    }
    if (start < 0) start = 0;
    if (nxt > N_ATOMS) nxt = N_ATOMS;

    int t = threadIdx.x;
    bool has1 = t < HIDDEN - 256;
    float sc0 = scale[t], sh0 = shift[t];
    float sc1 = 0.f, sh1 = 0.f;
    if (has1) { sc1 = scale[t + 256]; sh1 = shift[t + 256]; }
    float a0 = 0.f, a1 = 0.f;
    for (long long r = start; r < nxt; ++r) {
        const ST* row = h + (size_t)r * HIDDEN;
        a0 += fmaxf(fmaf(ld_val(&row[t]), sc0, sh0), 0.f);
        if (has1) a1 += fmaxf(fmaf(ld_val(&row[t + 256]), sc1, sh1), 0.f);
    }
    float den = (float)(len > 0 ? len : 1);
    out[(size_t)m * HIDDEN + t] = (len > 0) ? a0 / den : 0.f;
    if (has1) out[(size_t)m * HIDDEN + t + 256] = (len > 0) ? a1 / den : 0.f;
}

// ---------------------------------------------------------------------------
template<typename ST>
static void run_all(const float* fatoms, const float* fbonds,
                    const void* agraph, const void* bgraph, const void* scope,
                    const float* tree, const float* W_i, const float* W_h,
                    const float* W_o, const float* b_o,
                    const float* gamma, const float* beta,
                    float* out,
                    float* sums, float* sumsq, float* scale, float* shift,
                    char* bufbase, hipStream_t stream)
{
    ST* gm  = (ST*)bufbase;
    ST* nei = (ST*)(bufbase + (size_t)N_BONDS * HIDDEN * sizeof(ST));
    ST* h   = gm;   // gm is dead once the agraph gather has produced nei

    dim3 blk(256);
    dim3 gBond((N_BONDS + 63) / 64, (HIDDEN + 63) / 64);
    dim3 gAtom((N_ATOMS + 63) / 64, (HIDDEN + 63) / 64);

    // it0: gm = relu(fbonds @ W_i^T)            (A2/B2 are unused dummies)
    gemm_kernel<ST, false, true><<<gBond, blk, 0, stream>>>(
        fbonds, IN_FDIM, IN_FDIM, nei, HIDDEN,
        W_i, IN_FDIM, IN_FDIM, W_i, IN_FDIM,
        nullptr, gm, N_BONDS, HIDDEN, IN_FDIM);

    // it1..3: nei = gather(bgraph); gm = relu([fbonds|nei] @ [W_i|W_h]^T)
    for (int it = 0; it < DEPTH - 1; ++it) {
        gather_sum_kernel<ST><<<N_BONDS / 4, blk, 0, stream>>>(
            bgraph, N_BONDS, tree, gm, nei);
        gemm_kernel<ST, false, true><<<gBond, blk, 0, stream>>>(
            fbonds, IN_FDIM, IN_FDIM, nei, HIDDEN,
            W_i, IN_FDIM, IN_FDIM, W_h, HIDDEN,
            nullptr, gm, N_BONDS, HIDDEN, IN_FDIM + HIDDEN);
    }

    // atom side: nei = gather(agraph); h = [fatoms|nei] @ W_o^T + b_o
    gather_sum_kernel<ST><<<N_ATOMS / 4, blk, 0, stream>>>(
        agraph, N_ATOMS, tree, gm, nei);
    gemm_kernel<ST, true, false><<<gAtom, blk, 0, stream>>>(
        fatoms, ATOM_FDIM, ATOM_FDIM, nei, HIDDEN,
        W_o, ATOM_FDIM + HIDDEN, ATOM_FDIM + HIDDEN, W_o, ATOM_FDIM + HIDDEN,
        b_o, h, N_ATOMS, HIDDEN, ATOM_FDIM + HIDDEN);

    colstats_kernel<ST><<<120, blk, 0, stream>>>(h, sums, sumsq);
    finalize_stats_kernel<<<1, 512, 0, stream>>>(sums, sumsq, gamma, beta, scale, shift);
    pool_kernel<ST><<<N_MOLS, blk, 0, stream>>>(h, scope, scale, shift, out);
}

extern "C" void kernel_launch(void* const* d_in, const int* in_sizes, int n_in,
                              void* d_out, int out_size, void* d_ws, size_t ws_size,
                              hipStream_t stream)
{
    const float* fatoms = (const float*)d_in[0];
    const float* fbonds = (const float*)d_in[1];
    const void*  agraph = d_in[2];
    const void*  bgraph = d_in[3];
    const void*  scope  = d_in[4];
    const float* tree   = (const float*)d_in[5];
    const float* W_i    = (const float*)d_in[6];
    const float* W_h    = (const float*)d_in[7];
    const float* W_o    = (const float*)d_in[8];
    const float* b_o    = (const float*)d_in[9];
    const float* gamma  = (const float*)d_in[10];
    const float* beta   = (const float*)d_in[11];
    float* out = (float*)d_out;

    char* ws = (char*)d_ws;
    float* sums  = (float*)ws;
    float* sumsq = sums + HIDDEN;
    float* scale = sums + 2 * HIDDEN;
    float* shift = sums + 3 * HIDDEN;
    char* bufbase = ws + 65536;

    const size_t nelem = (size_t)N_BONDS * HIDDEN;   // 27e6 per buffer
    const bool f32_fits = ws_size >= 65536 + 2 * nelem * sizeof(float);

    zero_stats_kernel<<<4, 256, 0, stream>>>(sums);

    if (f32_fits) {
        run_all<float>(fatoms, fbonds, agraph, bgraph, scope, tree,
                       W_i, W_h, W_o, b_o, gamma, beta, out,
                       sums, sumsq, scale, shift, bufbase, stream);
    } else {
        run_all<__hip_bfloat16>(fatoms, fbonds, agraph, bgraph, scope, tree,
                                W_i, W_h, W_o, b_o, gamma, beta, out,
                                sums, sumsq, scale, shift, bufbase, stream);
    }
}

// Round 4
// 873.074 us; speedup vs baseline: 5.3479x; 5.3479x over previous
//
#include <hip/hip_runtime.h>
#include <cstdint>
#include <cstddef>

#define HIDDEN 450
#define ATOM_FDIM 35
#define IN_FDIM 40        // ATOM_FDIM + BOND_FDIM
#define MAX_NB 15
#define N_ATOMS 30000
#define N_BONDS 60000
#define N_MESS 10001
#define N_MOLS 1000
#define DEPTH 4
#define NTOT (N_MESS + N_BONDS)

#define KPAD 512          // padded K for concat GEMMs
#define MLD  464          // padded message-row length (450 -> 464, 58x8)
#define MB_PAD 60032      // N_BONDS padded to x128
#define MA_PAD 30080      // N_ATOMS padded to x128

typedef _Float16 f16x8_t __attribute__((ext_vector_type(8)));
typedef float f32x4_t __attribute__((ext_vector_type(4)));
typedef unsigned short ushort8_t __attribute__((ext_vector_type(8)));

// ---- helpers ---------------------------------------------------------------
__device__ __forceinline__ float h2f(unsigned short u) {
    return (float)__builtin_bit_cast(_Float16, u);
}
__device__ __forceinline__ unsigned short f2h(float f) {
    return __builtin_bit_cast(unsigned short, (_Float16)f);   // RNE v_cvt_f16_f32
}
__device__ __forceinline__ void st_out(unsigned short* p, float v) { *p = f2h(v); }
__device__ __forceinline__ void st_out(float* p, float v) { *p = v; }

__device__ __forceinline__ void g2l16(const unsigned short* g, unsigned short* l) {
    __builtin_amdgcn_global_load_lds(
        (const __attribute__((address_space(1))) void*)g,
        (__attribute__((address_space(3))) void*)l, 16, 0, 0);
}

// int64-vs-int32 sniff: int64 index arrays have zero high words
__device__ __forceinline__ bool sniff_is64(const void* g) {
    const int* g32 = (const int*)g;
    return (g32[1] | g32[3] | g32[5] | g32[7]) == 0;
}
__device__ __forceinline__ long long load_idx(const void* g, size_t pos, bool is64) {
    return is64 ? ((const long long*)g)[pos] : (long long)((const int*)g)[pos];
}

// ---- prep kernels ----------------------------------------------------------
__global__ void zero_stats_kernel(float* __restrict__ p) {
    int i = blockIdx.x * blockDim.x + threadIdx.x;
    if (i < 2 * HIDDEN) p[i] = 0.f;
}

// Wih[512][512]: rows<450: cols 0..39 = W_i, 40..489 = W_h, else 0
__global__ void build_wih_kernel(const float* __restrict__ W_i,
                                 const float* __restrict__ W_h,
                                 unsigned short* __restrict__ Wih) {
    int t = blockIdx.x * blockDim.x + threadIdx.x;
    if (t >= KPAD * KPAD) return;
    int n = t >> 9, k = t & 511;
    float v = 0.f;
    if (n < HIDDEN) {
        if (k < IN_FDIM)            v = W_i[(size_t)n * IN_FDIM + k];
        else if (k < IN_FDIM + HIDDEN) v = W_h[(size_t)n * HIDDEN + (k - IN_FDIM)];
    }
    Wih[t] = f2h(v);
}

// Wo[512][512]: rows<450: cols 0..34 = W_o[:,0:35], 40..489 = W_o[:,35:485]
__global__ void build_wo_kernel(const float* __restrict__ W_o,
                                unsigned short* __restrict__ Wo) {
    int t = blockIdx.x * blockDim.x + threadIdx.x;
    if (t >= KPAD * KPAD) return;
    int n = t >> 9, k = t & 511;
    float v = 0.f;
    if (n < HIDDEN) {
        if (k < ATOM_FDIM)                   v = W_o[(size_t)n * (ATOM_FDIM + HIDDEN) + k];
        else if (k >= IN_FDIM && k < IN_FDIM + HIDDEN)
            v = W_o[(size_t)n * (ATOM_FDIM + HIDDEN) + ATOM_FDIM + (k - IN_FDIM)];
    }
    Wo[t] = f2h(v);
}

// Abond[60032][512]: cols 0..39 = f16(fbonds), cols 40..511 = 0 (it0 + pads)
__global__ void cvt_fbonds_kernel(const float* __restrict__ fbonds,
                                  unsigned short* __restrict__ Ab) {
    int t = blockIdx.x * blockDim.x + threadIdx.x;
    if (t >= MB_PAD * 64) return;
    int r = t >> 6, c8 = (t & 63) * 8;
    ushort8_t o;
    #pragma unroll
    for (int j = 0; j < 8; ++j) {
        int c = c8 + j;
        float v = (r < N_BONDS && c < IN_FDIM) ? fbonds[(size_t)r * IN_FDIM + c] : 0.f;
        o[j] = f2h(v);
    }
    *(ushort8_t*)(Ab + (size_t)r * KPAD + c8) = o;
}

// Aatom[30080][512]: cols 0..34 = f16(fatoms), rest 0
__global__ void cvt_fatoms_kernel(const float* __restrict__ fatoms,
                                  unsigned short* __restrict__ Aa) {
    int t = blockIdx.x * blockDim.x + threadIdx.x;
    if (t >= MA_PAD * 64) return;
    int r = t >> 6, c8 = (t & 63) * 8;
    ushort8_t o;
    #pragma unroll
    for (int j = 0; j < 8; ++j) {
        int c = c8 + j;
        float v = (r < N_ATOMS && c < ATOM_FDIM) ? fatoms[(size_t)r * ATOM_FDIM + c] : 0.f;
        o[j] = f2h(v);
    }
    *(ushort8_t*)(Aa + (size_t)r * KPAD + c8) = o;
}

// tree_f16[10001][464]: cols<450 from fp32 tree, else 0
__global__ void cvt_tree_kernel(const float* __restrict__ tree,
                                unsigned short* __restrict__ tb) {
    int t = blockIdx.x * blockDim.x + threadIdx.x;
    if (t >= N_MESS * (MLD / 8)) return;
    int r = t / (MLD / 8), c8 = (t % (MLD / 8)) * 8;
    ushort8_t o;
    #pragma unroll
    for (int j = 0; j < 8; ++j) {
        int c = c8 + j;
        float v = (c < HIDDEN) ? tree[(size_t)r * HIDDEN + c] : 0.f;
        o[j] = f2h(v);
    }
    *(ushort8_t*)(tb + (size_t)r * MLD + c8) = o;
}

// zero gm pad cols 448..463 (GEMM later rewrites 448,449 with real data)
__global__ void zero_gmpad_kernel(unsigned short* __restrict__ gm) {
    int r = blockIdx.x * blockDim.x + threadIdx.x;
    if (r >= N_BONDS) return;
    ushort8_t z = {0, 0, 0, 0, 0, 0, 0, 0};
    *(ushort8_t*)(gm + (size_t)r * MLD + 448) = z;
    *(ushort8_t*)(gm + (size_t)r * MLD + 456) = z;
}

// ---- MFMA GEMM: Out = act(A @ B^T [+bias]) ---------------------------------
// A [Mpad][512] f16 row-major, B [512][512] f16 row-major (rows >=450 zero).
// 128x128 tile, BK=32, 4 waves (2x2), each wave 4x4 frags of 16x16x32.
template<bool RELU, bool BIAS, typename OT>
__global__ __launch_bounds__(256)
void mfma_gemm_kernel(const unsigned short* __restrict__ A,
                      const unsigned short* __restrict__ B,
                      const float* __restrict__ bias,
                      OT* __restrict__ Out, int ldo,
                      int M, int Nvalid)
{
    __shared__ unsigned short As[128 * 32];
    __shared__ unsigned short Bs[128 * 32];
    const int tid  = threadIdx.x;
    const int wave = tid >> 6, lane = tid & 63;
    const int m0 = blockIdx.x * 128, n0 = blockIdx.y * 128;
    const int wm = wave >> 1, wn = wave & 1;

    const unsigned short* At = A + (size_t)m0 * KPAD;
    const unsigned short* Bt = B + (size_t)n0 * KPAD;

    // staging: chunk c covers LDS bytes [c*16, c*16+16) = row c>>2, k8 (c&3)*8
    const int c0 = wave * 128 + lane;
    const int c1 = c0 + 64;
    const int rA0 = c0 >> 2, kc0 = (c0 & 3) * 8;
    const int rA1 = c1 >> 2, kc1 = (c1 & 3) * 8;
    unsigned short* lA0 = &As[(size_t)(wave * 128) * 8];
    unsigned short* lA1 = &As[(size_t)(wave * 128 + 64) * 8];
    unsigned short* lB0 = &Bs[(size_t)(wave * 128) * 8];
    unsigned short* lB1 = &Bs[(size_t)(wave * 128 + 64) * 8];

    const int fr = lane & 15, kof = (lane >> 4) * 8;

    f32x4_t acc[4][4];
    #pragma unroll
    for (int mi = 0; mi < 4; ++mi)
        #pragma unroll
        for (int ni = 0; ni < 4; ++ni)
            acc[mi][ni] = f32x4_t{0.f, 0.f, 0.f, 0.f};

    for (int k0 = 0; k0 < KPAD; k0 += 32) {
        g2l16(At + (size_t)rA0 * KPAD + k0 + kc0, lA0);
        g2l16(At + (size_t)rA1 * KPAD + k0 + kc1, lA1);
        g2l16(Bt + (size_t)rA0 * KPAD + k0 + kc0, lB0);
        g2l16(Bt + (size_t)rA1 * KPAD + k0 + kc1, lB1);
        __syncthreads();

        f16x8_t a[4], b[4];
        #pragma unroll
        for (int mi = 0; mi < 4; ++mi)
            a[mi] = __builtin_bit_cast(f16x8_t,
                *(const ushort8_t*)&As[(size_t)((wm * 64 + mi * 16 + fr) * 32 + kof)]);
        #pragma unroll
        for (int ni = 0; ni < 4; ++ni)
            b[ni] = __builtin_bit_cast(f16x8_t,
                *(const ushort8_t*)&Bs[(size_t)((wn * 64 + ni * 16 + fr) * 32 + kof)]);
        #pragma unroll
        for (int mi = 0; mi < 4; ++mi)
            #pragma unroll
            for (int ni = 0; ni < 4; ++ni)
                acc[mi][ni] = __builtin_amdgcn_mfma_f32_16x16x32_f16(
                    a[mi], b[ni], acc[mi][ni], 0, 0, 0);
        __syncthreads();
    }

    // epilogue: C/D layout col=lane&15, row=(lane>>4)*4+reg  [m89/m91]
    #pragma unroll
    for (int mi = 0; mi < 4; ++mi) {
        int row_b = m0 + wm * 64 + mi * 16 + (lane >> 4) * 4;
        #pragma unroll
        for (int ni = 0; ni < 4; ++ni) {
            int col = n0 + wn * 64 + ni * 16 + fr;
            if (col >= Nvalid) continue;
            float bi = BIAS ? bias[col] : 0.f;
            #pragma unroll
            for (int r = 0; r < 4; ++r) {
                int row = row_b + r;
                if (row >= M) continue;
                float v = acc[mi][ni][r] + bi;
                if (RELU) v = fmaxf(v, 0.f);
                st_out(&Out[(size_t)row * ldo + col], v);
            }
        }
    }
}

// ---- gather-sum (f16 tables, ld=464) -> Adst cols [40,496) (ld=512) --------
__global__ __launch_bounds__(256)
void gather_kernel(const void* __restrict__ graph, int n_rows,
                   const unsigned short* __restrict__ tree,
                   const unsigned short* __restrict__ gm,
                   unsigned short* __restrict__ Adst)
{
    __shared__ bool is64_s;
    if (threadIdx.x == 0) is64_s = sniff_is64(graph);
    __syncthreads();
    const bool is64 = is64_s;

    int w    = (int)((blockIdx.x * 256 + threadIdx.x) >> 6);
    int lane = threadIdx.x & 63;
    if (w >= n_rows) return;
    const bool act = lane < 57;          // 57*8 = 456 cols (450 data + 6 zero-pad)
    const size_t coff = (size_t)lane * 8;

    float acc[8] = {};
    for (int nb = 0; nb < MAX_NB; ++nb) {
        long long idx = load_idx(graph, (size_t)w * MAX_NB + nb, is64);
        if (idx < 0) idx = 0;
        if (idx >= NTOT) idx = NTOT - 1;
        const unsigned short* row = (idx < N_MESS)
            ? tree + (size_t)idx * MLD
            : gm + (size_t)(idx - N_MESS) * MLD;
        if (act) {
            ushort8_t v = *(const ushort8_t*)(row + coff);
            #pragma unroll
            for (int j = 0; j < 8; ++j) acc[j] += h2f(v[j]);
        }
    }
    if (act) {
        ushort8_t o;
        #pragma unroll
        for (int j = 0; j < 8; ++j) o[j] = f2h(acc[j]);
        *(ushort8_t*)(Adst + (size_t)w * KPAD + IN_FDIM + coff) = o;
    }
}

// ---- column stats over h[30000][450] fp32 ----------------------------------
__global__ __launch_bounds__(256)
void colstats_kernel(const float* __restrict__ h,
                     float* __restrict__ sums, float* __restrict__ sumsq)
{
    int t = threadIdx.x;
    int r0 = blockIdx.x * 250;
    float s0 = 0.f, q0 = 0.f, s1 = 0.f, q1 = 0.f;
    bool has1 = t < HIDDEN - 256;
    for (int r = r0; r < r0 + 250; ++r) {
        const float* row = h + (size_t)r * HIDDEN;
        float v0 = row[t];
        s0 += v0; q0 += v0 * v0;
        if (has1) {
            float v1 = row[t + 256];
            s1 += v1; q1 += v1 * v1;
        }
    }
    atomicAdd(&sums[t], s0);
    atomicAdd(&sumsq[t], q0);
    if (has1) {
        atomicAdd(&sums[t + 256], s1);
        atomicAdd(&sumsq[t + 256], q1);
    }
}

__global__ void finalize_stats_kernel(const float* __restrict__ sums,
                                      const float* __restrict__ sumsq,
                                      const float* __restrict__ gamma,
                                      const float* __restrict__ beta,
                                      float* __restrict__ scale,
                                      float* __restrict__ shift)
{
    int c = blockIdx.x * blockDim.x + threadIdx.x;
    if (c >= HIDDEN) return;
    float mean = sums[c] * (1.f / N_ATOMS);
    float var  = sumsq[c] * (1.f / N_ATOMS) - mean * mean;
    float inv  = rsqrtf(var + 1e-5f);
    float sc   = gamma[c] * inv;
    scale[c] = sc;
    shift[c] = beta[c] - mean * sc;
}

// ---- per-mol mean of relu(h*scale + shift) ---------------------------------
__global__ __launch_bounds__(256)
void pool_kernel(const float* __restrict__ h, const void* __restrict__ scope,
                 const float* __restrict__ scale, const float* __restrict__ shift,
                 float* __restrict__ out)
{
    int m = blockIdx.x;
    const int* s32 = (const int*)scope;
    bool is64 = (s32[1] == 0 && s32[3] == 0);
    long long start, len, nxt;
    if (is64) {
        const long long* s = (const long long*)scope;
        start = s[2 * m]; len = s[2 * m + 1];
        nxt = (m < N_MOLS - 1) ? s[2 * m + 2] : (long long)N_ATOMS;
    } else {
        start = s32[2 * m]; len = s32[2 * m + 1];
        nxt = (m < N_MOLS - 1) ? (long long)s32[2 * m + 2] : (long long)N_ATOMS;
    }
    if (start < 0) start = 0;
    if (nxt > N_ATOMS) nxt = N_ATOMS;

    int t = threadIdx.x;
    bool has1 = t < HIDDEN - 256;
    float sc0 = scale[t], sh0 = shift[t];
    float sc1 = 0.f, sh1 = 0.f;
    if (has1) { sc1 = scale[t + 256]; sh1 = shift[t + 256]; }
    float a0 = 0.f, a1 = 0.f;
    for (long long r = start; r < nxt; ++r) {
        const float* row = h + (size_t)r * HIDDEN;
        a0 += fmaxf(fmaf(row[t], sc0, sh0), 0.f);
        if (has1) a1 += fmaxf(fmaf(row[t + 256], sc1, sh1), 0.f);
    }
    float den = (float)(len > 0 ? len : 1);
    out[(size_t)m * HIDDEN + t] = (len > 0) ? a0 / den : 0.f;
    if (has1) out[(size_t)m * HIDDEN + t + 256] = (len > 0) ? a1 / den : 0.f;
}

// ---------------------------------------------------------------------------
extern "C" void kernel_launch(void* const* d_in, const int* in_sizes, int n_in,
                              void* d_out, int out_size, void* d_ws, size_t ws_size,
                              hipStream_t stream)
{
    const float* fatoms = (const float*)d_in[0];
    const float* fbonds = (const float*)d_in[1];
    const void*  agraph = d_in[2];
    const void*  bgraph = d_in[3];
    const void*  scope  = d_in[4];
    const float* tree   = (const float*)d_in[5];
    const float* W_i    = (const float*)d_in[6];
    const float* W_h    = (const float*)d_in[7];
    const float* W_o    = (const float*)d_in[8];
    const float* b_o    = (const float*)d_in[9];
    const float* gamma  = (const float*)d_in[10];
    const float* beta   = (const float*)d_in[11];
    float* out = (float*)d_out;

    // ---- workspace layout (all offsets 256B aligned) ----
    char* ws = (char*)d_ws;
    size_t off = 0;
    auto alloc = [&](size_t bytes) { char* p = ws + off; off += (bytes + 255) & ~(size_t)255; return p; };
    float*          sums  = (float*)alloc(4 * HIDDEN * sizeof(float));
    float*          sumsq = sums + HIDDEN;
    float*          scale = sums + 2 * HIDDEN;
    float*          shift = sums + 3 * HIDDEN;
    unsigned short* Abond = (unsigned short*)alloc((size_t)MB_PAD * KPAD * 2);
    unsigned short* Aatom = (unsigned short*)alloc((size_t)MA_PAD * KPAD * 2);
    unsigned short* gm    = (unsigned short*)alloc((size_t)N_BONDS * MLD * 2);
    unsigned short* tb    = (unsigned short*)alloc((size_t)N_MESS * MLD * 2);
    unsigned short* Wih   = (unsigned short*)alloc((size_t)KPAD * KPAD * 2);
    unsigned short* Wo    = (unsigned short*)alloc((size_t)KPAD * KPAD * 2);
    float*          h     = (float*)alloc((size_t)N_ATOMS * HIDDEN * sizeof(float));
    (void)ws_size;

    dim3 blk(256);

    // ---- prep ----
    zero_stats_kernel<<<4, blk, 0, stream>>>(sums);
    build_wih_kernel<<<(KPAD * KPAD + 255) / 256, blk, 0, stream>>>(W_i, W_h, Wih);
    build_wo_kernel<<<(KPAD * KPAD + 255) / 256, blk, 0, stream>>>(W_o, Wo);
    cvt_fbonds_kernel<<<(MB_PAD * 64 + 255) / 256, blk, 0, stream>>>(fbonds, Abond);
    cvt_fatoms_kernel<<<(MA_PAD * 64 + 255) / 256, blk, 0, stream>>>(fatoms, Aatom);
    cvt_tree_kernel<<<(N_MESS * (MLD / 8) + 255) / 256, blk, 0, stream>>>(tree, tb);
    zero_gmpad_kernel<<<(N_BONDS + 255) / 256, blk, 0, stream>>>(gm);

    dim3 gBond(MB_PAD / 128, 4);
    dim3 gAtom(MA_PAD / 128, 4);

    // it0: gm = relu(fbonds @ W_i^T)   (nei cols of Abond are zero)
    mfma_gemm_kernel<true, false, unsigned short><<<gBond, blk, 0, stream>>>(
        Abond, Wih, nullptr, gm, MLD, N_BONDS, HIDDEN);

    // it1..3: nei = gather(bgraph); gm = relu([fbonds|nei] @ [W_i|W_h]^T)
    for (int it = 0; it < DEPTH - 1; ++it) {
        gather_kernel<<<N_BONDS / 4, blk, 0, stream>>>(bgraph, N_BONDS, tb, gm, Abond);
        mfma_gemm_kernel<true, false, unsigned short><<<gBond, blk, 0, stream>>>(
            Abond, Wih, nullptr, gm, MLD, N_BONDS, HIDDEN);
    }

    // atom side: nei = gather(agraph); h = [fatoms|nei] @ W_o^T + b_o
    gather_kernel<<<N_ATOMS / 4, blk, 0, stream>>>(agraph, N_ATOMS, tb, gm, Aatom);
    mfma_gemm_kernel<false, true, float><<<gAtom, blk, 0, stream>>>(
        Aatom, Wo, b_o, h, HIDDEN, N_ATOMS, HIDDEN);

    // layernorm stats + pool
    colstats_kernel<<<120, blk, 0, stream>>>(h, sums, sumsq);
    finalize_stats_kernel<<<1, 512, 0, stream>>>(sums, sumsq, gamma, beta, scale, shift);
    pool_kernel<<<N_MOLS, blk, 0, stream>>>(h, scope, scale, shift, out);
}

// Round 5
// 849.364 us; speedup vs baseline: 5.4972x; 1.0279x over previous
//
#include <hip/hip_runtime.h>
#include <cstdint>
#include <cstddef>

#define HIDDEN 450
#define ATOM_FDIM 35
#define IN_FDIM 40        // ATOM_FDIM + BOND_FDIM
#define MAX_NB 15
#define N_ATOMS 30000
#define N_BONDS 60000
#define N_MESS 10001
#define N_MOLS 1000
#define DEPTH 4
#define NTOT (N_MESS + N_BONDS)

#define KPAD 512          // padded K for concat GEMMs
#define MLD  464          // padded message-row length (450 -> 464, 58x8)
#define MB_PAD 60032      // N_BONDS padded to x128
#define MA_PAD 30080      // N_ATOMS padded to x128

typedef _Float16 f16x8_t __attribute__((ext_vector_type(8)));
typedef float f32x4_t __attribute__((ext_vector_type(4)));
typedef unsigned short ushort8_t __attribute__((ext_vector_type(8)));

// ---- helpers ---------------------------------------------------------------
__device__ __forceinline__ float h2f(unsigned short u) {
    return (float)__builtin_bit_cast(_Float16, u);
}
__device__ __forceinline__ unsigned short f2h(float f) {
    return __builtin_bit_cast(unsigned short, (_Float16)f);   // RNE v_cvt_f16_f32
}
__device__ __forceinline__ void st_out(unsigned short* p, float v) { *p = f2h(v); }
__device__ __forceinline__ void st_out(float* p, float v) { *p = v; }

__device__ __forceinline__ void g2l16(const unsigned short* g, unsigned short* l) {
    __builtin_amdgcn_global_load_lds(
        (const __attribute__((address_space(1))) void*)g,
        (__attribute__((address_space(3))) void*)l, 16, 0, 0);
}

// int64-vs-int32 sniff: int64 index arrays have zero high words
__device__ __forceinline__ bool sniff_is64(const void* g) {
    const int* g32 = (const int*)g;
    return (g32[1] | g32[3] | g32[5] | g32[7]) == 0;
}
__device__ __forceinline__ long long load_idx(const void* g, size_t pos, bool is64) {
    return is64 ? ((const long long*)g)[pos] : (long long)((const int*)g)[pos];
}

// ---- prep kernels ----------------------------------------------------------
__global__ void zero_stats_kernel(float* __restrict__ p) {
    int i = blockIdx.x * blockDim.x + threadIdx.x;
    if (i < 2 * HIDDEN) p[i] = 0.f;
}

// Wih[512][512]: rows<450: cols 0..39 = W_i, 40..489 = W_h, else 0
__global__ void build_wih_kernel(const float* __restrict__ W_i,
                                 const float* __restrict__ W_h,
                                 unsigned short* __restrict__ Wih) {
    int t = blockIdx.x * blockDim.x + threadIdx.x;
    if (t >= KPAD * KPAD) return;
    int n = t >> 9, k = t & 511;
    float v = 0.f;
    if (n < HIDDEN) {
        if (k < IN_FDIM)            v = W_i[(size_t)n * IN_FDIM + k];
        else if (k < IN_FDIM + HIDDEN) v = W_h[(size_t)n * HIDDEN + (k - IN_FDIM)];
    }
    Wih[t] = f2h(v);
}

// Wo[512][512]: rows<450: cols 0..34 = W_o[:,0:35], 40..489 = W_o[:,35:485]
__global__ void build_wo_kernel(const float* __restrict__ W_o,
                                unsigned short* __restrict__ Wo) {
    int t = blockIdx.x * blockDim.x + threadIdx.x;
    if (t >= KPAD * KPAD) return;
    int n = t >> 9, k = t & 511;
    float v = 0.f;
    if (n < HIDDEN) {
        if (k < ATOM_FDIM)                   v = W_o[(size_t)n * (ATOM_FDIM + HIDDEN) + k];
        else if (k >= IN_FDIM && k < IN_FDIM + HIDDEN)
            v = W_o[(size_t)n * (ATOM_FDIM + HIDDEN) + ATOM_FDIM + (k - IN_FDIM)];
    }
    Wo[t] = f2h(v);
}

// Abond[60032][512]: cols 0..39 = f16(fbonds), cols 40..511 = 0 (it0 + pads)
__global__ void cvt_fbonds_kernel(const float* __restrict__ fbonds,
                                  unsigned short* __restrict__ Ab) {
    int t = blockIdx.x * blockDim.x + threadIdx.x;
    if (t >= MB_PAD * 64) return;
    int r = t >> 6, c8 = (t & 63) * 8;
    ushort8_t o;
    #pragma unroll
    for (int j = 0; j < 8; ++j) {
        int c = c8 + j;
        float v = (r < N_BONDS && c < IN_FDIM) ? fbonds[(size_t)r * IN_FDIM + c] : 0.f;
        o[j] = f2h(v);
    }
    *(ushort8_t*)(Ab + (size_t)r * KPAD + c8) = o;
}

// Aatom[30080][512]: cols 0..34 = f16(fatoms), rest 0
__global__ void cvt_fatoms_kernel(const float* __restrict__ fatoms,
                                  unsigned short* __restrict__ Aa) {
    int t = blockIdx.x * blockDim.x + threadIdx.x;
    if (t >= MA_PAD * 64) return;
    int r = t >> 6, c8 = (t & 63) * 8;
    ushort8_t o;
    #pragma unroll
    for (int j = 0; j < 8; ++j) {
        int c = c8 + j;
        float v = (r < N_ATOMS && c < ATOM_FDIM) ? fatoms[(size_t)r * ATOM_FDIM + c] : 0.f;
        o[j] = f2h(v);
    }
    *(ushort8_t*)(Aa + (size_t)r * KPAD + c8) = o;
}

// tree_f16[10001][464]: cols<450 from fp32 tree, else 0
__global__ void cvt_tree_kernel(const float* __restrict__ tree,
                                unsigned short* __restrict__ tb) {
    int t = blockIdx.x * blockDim.x + threadIdx.x;
    if (t >= N_MESS * (MLD / 8)) return;
    int r = t / (MLD / 8), c8 = (t % (MLD / 8)) * 8;
    ushort8_t o;
    #pragma unroll
    for (int j = 0; j < 8; ++j) {
        int c = c8 + j;
        float v = (c < HIDDEN) ? tree[(size_t)r * HIDDEN + c] : 0.f;
        o[j] = f2h(v);
    }
    *(ushort8_t*)(tb + (size_t)r * MLD + c8) = o;
}

// zero gm pad cols 448..463 (GEMM later rewrites 448,449 with real data)
__global__ void zero_gmpad_kernel(unsigned short* __restrict__ gm) {
    int r = blockIdx.x * blockDim.x + threadIdx.x;
    if (r >= N_BONDS) return;
    ushort8_t z = {0, 0, 0, 0, 0, 0, 0, 0};
    *(ushort8_t*)(gm + (size_t)r * MLD + 448) = z;
    *(ushort8_t*)(gm + (size_t)r * MLD + 456) = z;
}

// ---- MFMA GEMM: Out = act(A @ B^T [+bias]) ---------------------------------
// A [Mpad][512] f16 row-major, B [512][512] f16 row-major (rows >=450 zero).
// 128x128 tile, BK=32, 4 waves (2x2), each wave 4x4 frags of 16x16x32.
// K is runtime (multiple of 32): it0 only needs K=64.
template<bool RELU, bool BIAS, typename OT>
__global__ __launch_bounds__(256)
void mfma_gemm_kernel(const unsigned short* __restrict__ A,
                      const unsigned short* __restrict__ B,
                      const float* __restrict__ bias,
                      OT* __restrict__ Out, int ldo,
                      int M, int Nvalid, int K)
{
    __shared__ unsigned short As[128 * 32];
    __shared__ unsigned short Bs[128 * 32];
    const int tid  = threadIdx.x;
    const int wave = tid >> 6, lane = tid & 63;
    const int m0 = blockIdx.x * 128, n0 = blockIdx.y * 128;
    const int wm = wave >> 1, wn = wave & 1;

    const unsigned short* At = A + (size_t)m0 * KPAD;
    const unsigned short* Bt = B + (size_t)n0 * KPAD;

    // staging: chunk c covers LDS bytes [c*16, c*16+16) = row c>>2, k8 (c&3)*8
    const int c0 = wave * 128 + lane;
    const int c1 = c0 + 64;
    const int rA0 = c0 >> 2, kc0 = (c0 & 3) * 8;
    const int rA1 = c1 >> 2, kc1 = (c1 & 3) * 8;
    unsigned short* lA0 = &As[(size_t)(wave * 128) * 8];
    unsigned short* lA1 = &As[(size_t)(wave * 128 + 64) * 8];
    unsigned short* lB0 = &Bs[(size_t)(wave * 128) * 8];
    unsigned short* lB1 = &Bs[(size_t)(wave * 128 + 64) * 8];

    const int fr = lane & 15, kof = (lane >> 4) * 8;

    f32x4_t acc[4][4];
    #pragma unroll
    for (int mi = 0; mi < 4; ++mi)
        #pragma unroll
        for (int ni = 0; ni < 4; ++ni)
            acc[mi][ni] = f32x4_t{0.f, 0.f, 0.f, 0.f};

    for (int k0 = 0; k0 < K; k0 += 32) {
        g2l16(At + (size_t)rA0 * KPAD + k0 + kc0, lA0);
        g2l16(At + (size_t)rA1 * KPAD + k0 + kc1, lA1);
        g2l16(Bt + (size_t)rA0 * KPAD + k0 + kc0, lB0);
        g2l16(Bt + (size_t)rA1 * KPAD + k0 + kc1, lB1);
        __syncthreads();

        f16x8_t a[4], b[4];
        #pragma unroll
        for (int mi = 0; mi < 4; ++mi)
            a[mi] = __builtin_bit_cast(f16x8_t,
                *(const ushort8_t*)&As[(size_t)((wm * 64 + mi * 16 + fr) * 32 + kof)]);
        #pragma unroll
        for (int ni = 0; ni < 4; ++ni)
            b[ni] = __builtin_bit_cast(f16x8_t,
                *(const ushort8_t*)&Bs[(size_t)((wn * 64 + ni * 16 + fr) * 32 + kof)]);
        #pragma unroll
        for (int mi = 0; mi < 4; ++mi)
            #pragma unroll
            for (int ni = 0; ni < 4; ++ni)
                acc[mi][ni] = __builtin_amdgcn_mfma_f32_16x16x32_f16(
                    a[mi], b[ni], acc[mi][ni], 0, 0, 0);
        __syncthreads();
    }

    // epilogue: C/D layout col=lane&15, row=(lane>>4)*4+reg  [m89/m91]
    #pragma unroll
    for (int mi = 0; mi < 4; ++mi) {
        int row_b = m0 + wm * 64 + mi * 16 + (lane >> 4) * 4;
        #pragma unroll
        for (int ni = 0; ni < 4; ++ni) {
            int col = n0 + wn * 64 + ni * 16 + fr;
            if (col >= Nvalid) continue;
            float bi = BIAS ? bias[col] : 0.f;
            #pragma unroll
            for (int r = 0; r < 4; ++r) {
                int row = row_b + r;
                if (row >= M) continue;
                float v = acc[mi][ni][r] + bi;
                if (RELU) v = fmaxf(v, 0.f);
                st_out(&Out[(size_t)row * ldo + col], v);
            }
        }
    }
}

// ---- gather-sum (f16 tables, ld=464) -> Adst cols [40,496) (ld=512) --------
// One wave per output row. The 15 indices are wave-uniform -> SGPR via
// readfirstlane; all 15 row-segment loads issued back-to-back (15-deep MLP),
// then accumulated in fp32.
__global__ __launch_bounds__(256)
void gather_kernel(const void* __restrict__ graph, int n_rows,
                   const unsigned short* __restrict__ tree,
                   const unsigned short* __restrict__ gm,
                   unsigned short* __restrict__ Adst)
{
    const bool is64 = sniff_is64(graph);
    int w    = (int)((blockIdx.x * 256 + threadIdx.x) >> 6);
    int lane = threadIdx.x & 63;
    if (w >= n_rows) return;
    const bool act = lane < 57;          // 57*8 = 456 cols (450 data + 6 zero-pad)
    const size_t coff = (size_t)(act ? lane : 0) * 8;

    // wave-uniform row pointers in SGPRs
    const unsigned short* rp[MAX_NB];
    #pragma unroll
    for (int nb = 0; nb < MAX_NB; ++nb) {
        long long idx = load_idx(graph, (size_t)w * MAX_NB + nb, is64);
        if (idx < 0) idx = 0;
        if (idx >= NTOT) idx = NTOT - 1;
        int i32 = __builtin_amdgcn_readfirstlane((int)idx);
        rp[nb] = (i32 < N_MESS) ? tree + (size_t)i32 * MLD
                                : gm + (size_t)(i32 - N_MESS) * MLD;
    }
    // issue all 15 loads, then reduce
    ushort8_t v[MAX_NB];
    #pragma unroll
    for (int nb = 0; nb < MAX_NB; ++nb)
        v[nb] = *(const ushort8_t*)(rp[nb] + coff);

    float acc[8] = {};
    #pragma unroll
    for (int nb = 0; nb < MAX_NB; ++nb)
        #pragma unroll
        for (int j = 0; j < 8; ++j)
            acc[j] += h2f(v[nb][j]);

    if (act) {
        ushort8_t o;
        #pragma unroll
        for (int j = 0; j < 8; ++j) o[j] = f2h(acc[j]);
        *(ushort8_t*)(Adst + (size_t)w * KPAD + IN_FDIM + (size_t)lane * 8) = o;
    }
}

// ---- column stats over h[30000][450] fp32 ----------------------------------
__global__ __launch_bounds__(256)
void colstats_kernel(const float* __restrict__ h,
                     float* __restrict__ sums, float* __restrict__ sumsq)
{
    int t = threadIdx.x;
    int r0 = blockIdx.x * 250;
    float s0 = 0.f, q0 = 0.f, s1 = 0.f, q1 = 0.f;
    bool has1 = t < HIDDEN - 256;
    for (int r = r0; r < r0 + 250; ++r) {
        const float* row = h + (size_t)r * HIDDEN;
        float v0 = row[t];
        s0 += v0; q0 += v0 * v0;
        if (has1) {
            float v1 = row[t + 256];
            s1 += v1; q1 += v1 * v1;
        }
    }
    atomicAdd(&sums[t], s0);
    atomicAdd(&sumsq[t], q0);
    if (has1) {
        atomicAdd(&sums[t + 256], s1);
        atomicAdd(&sumsq[t + 256], q1);
    }
}

__global__ void finalize_stats_kernel(const float* __restrict__ sums,
                                      const float* __restrict__ sumsq,
                                      const float* __restrict__ gamma,
                                      const float* __restrict__ beta,
                                      float* __restrict__ scale,
                                      float* __restrict__ shift)
{
    int c = blockIdx.x * blockDim.x + threadIdx.x;
    if (c >= HIDDEN) return;
    float mean = sums[c] * (1.f / N_ATOMS);
    float var  = sumsq[c] * (1.f / N_ATOMS) - mean * mean;
    float inv  = rsqrtf(var + 1e-5f);
    float sc   = gamma[c] * inv;
    scale[c] = sc;
    shift[c] = beta[c] - mean * sc;
}

// ---- per-mol mean of relu(h*scale + shift) ---------------------------------
__global__ __launch_bounds__(256)
void pool_kernel(const float* __restrict__ h, const void* __restrict__ scope,
                 const float* __restrict__ scale, const float* __restrict__ shift,
                 float* __restrict__ out)
{
    int m = blockIdx.x;
    const int* s32 = (const int*)scope;
    bool is64 = (s32[1] == 0 && s32[3] == 0);
    long long start, len, nxt;
    if (is64) {
        const long long* s = (const long long*)scope;
        start = s[2 * m]; len = s[2 * m + 1];
        nxt = (m < N_MOLS - 1) ? s[2 * m + 2] : (long long)N_ATOMS;
    } else {
        start = s32[2 * m]; len = s32[2 * m + 1];
        nxt = (m < N_MOLS - 1) ? (long long)s32[2 * m + 2] : (long long)N_ATOMS;
    }
    if (start < 0) start = 0;
    if (nxt > N_ATOMS) nxt = N_ATOMS;

    int t = threadIdx.x;
    bool has1 = t < HIDDEN - 256;
    float sc0 = scale[t], sh0 = shift[t];
    float sc1 = 0.f, sh1 = 0.f;
    if (has1) { sc1 = scale[t + 256]; sh1 = shift[t + 256]; }
    float a0 = 0.f, a1 = 0.f;
    for (long long r = start; r < nxt; ++r) {
        const float* row = h + (size_t)r * HIDDEN;
        a0 += fmaxf(fmaf(row[t], sc0, sh0), 0.f);
        if (has1) a1 += fmaxf(fmaf(row[t + 256], sc1, sh1), 0.f);
    }
    float den = (float)(len > 0 ? len : 1);
    out[(size_t)m * HIDDEN + t] = (len > 0) ? a0 / den : 0.f;
    if (has1) out[(size_t)m * HIDDEN + t + 256] = (len > 0) ? a1 / den : 0.f;
}

// ---------------------------------------------------------------------------
extern "C" void kernel_launch(void* const* d_in, const int* in_sizes, int n_in,
                              void* d_out, int out_size, void* d_ws, size_t ws_size,
                              hipStream_t stream)
{
    const float* fatoms = (const float*)d_in[0];
    const float* fbonds = (const float*)d_in[1];
    const void*  agraph = d_in[2];
    const void*  bgraph = d_in[3];
    const void*  scope  = d_in[4];
    const float* tree   = (const float*)d_in[5];
    const float* W_i    = (const float*)d_in[6];
    const float* W_h    = (const float*)d_in[7];
    const float* W_o    = (const float*)d_in[8];
    const float* b_o    = (const float*)d_in[9];
    const float* gamma  = (const float*)d_in[10];
    const float* beta   = (const float*)d_in[11];
    float* out = (float*)d_out;

    // ---- workspace layout (all offsets 256B aligned) ----
    char* ws = (char*)d_ws;
    size_t off = 0;
    auto alloc = [&](size_t bytes) { char* p = ws + off; off += (bytes + 255) & ~(size_t)255; return p; };
    float*          sums  = (float*)alloc(4 * HIDDEN * sizeof(float));
    float*          sumsq = sums + HIDDEN;
    float*          scale = sums + 2 * HIDDEN;
    float*          shift = sums + 3 * HIDDEN;
    unsigned short* Abond = (unsigned short*)alloc((size_t)MB_PAD * KPAD * 2);
    unsigned short* Aatom = (unsigned short*)alloc((size_t)MA_PAD * KPAD * 2);
    unsigned short* gm    = (unsigned short*)alloc((size_t)N_BONDS * MLD * 2);
    unsigned short* tb    = (unsigned short*)alloc((size_t)N_MESS * MLD * 2);
    unsigned short* Wih   = (unsigned short*)alloc((size_t)KPAD * KPAD * 2);
    unsigned short* Wo    = (unsigned short*)alloc((size_t)KPAD * KPAD * 2);
    float*          h     = (float*)alloc((size_t)N_ATOMS * HIDDEN * sizeof(float));
    (void)ws_size;

    dim3 blk(256);

    // ---- prep ----
    zero_stats_kernel<<<4, blk, 0, stream>>>(sums);
    build_wih_kernel<<<(KPAD * KPAD + 255) / 256, blk, 0, stream>>>(W_i, W_h, Wih);
    build_wo_kernel<<<(KPAD * KPAD + 255) / 256, blk, 0, stream>>>(W_o, Wo);
    cvt_fbonds_kernel<<<(MB_PAD * 64 + 255) / 256, blk, 0, stream>>>(fbonds, Abond);
    cvt_fatoms_kernel<<<(MA_PAD * 64 + 255) / 256, blk, 0, stream>>>(fatoms, Aatom);
    cvt_tree_kernel<<<(N_MESS * (MLD / 8) + 255) / 256, blk, 0, stream>>>(tree, tb);
    zero_gmpad_kernel<<<(N_BONDS + 255) / 256, blk, 0, stream>>>(gm);

    dim3 gBond(MB_PAD / 128, 4);
    dim3 gAtom(MA_PAD / 128, 4);

    // it0: gm = relu(fbonds @ W_i^T)   (nei cols of Abond are zero -> K=64)
    mfma_gemm_kernel<true, false, unsigned short><<<gBond, blk, 0, stream>>>(
        Abond, Wih, nullptr, gm, MLD, N_BONDS, HIDDEN, 64);

    // it1..3: nei = gather(bgraph); gm = relu([fbonds|nei] @ [W_i|W_h]^T)
    for (int it = 0; it < DEPTH - 1; ++it) {
        gather_kernel<<<N_BONDS / 4, blk, 0, stream>>>(bgraph, N_BONDS, tb, gm, Abond);
        mfma_gemm_kernel<true, false, unsigned short><<<gBond, blk, 0, stream>>>(
            Abond, Wih, nullptr, gm, MLD, N_BONDS, HIDDEN, KPAD);
    }

    // atom side: nei = gather(agraph); h = [fatoms|nei] @ W_o^T + b_o
    gather_kernel<<<N_ATOMS / 4, blk, 0, stream>>>(agraph, N_ATOMS, tb, gm, Aatom);
    mfma_gemm_kernel<false, true, float><<<gAtom, blk, 0, stream>>>(
        Aatom, Wo, b_o, h, HIDDEN, N_ATOMS, HIDDEN, KPAD);

    // layernorm stats + pool
    colstats_kernel<<<120, blk, 0, stream>>>(h, sums, sumsq);
    finalize_stats_kernel<<<1, 512, 0, stream>>>(sums, sumsq, gamma, beta, scale, shift);
    pool_kernel<<<N_MOLS, blk, 0, stream>>>(h, scope, scale, shift, out);
}

// Round 6
// 800.420 us; speedup vs baseline: 5.8333x; 1.0611x over previous
//
#include <hip/hip_runtime.h>
#include <cstdint>
#include <cstddef>

#define HIDDEN 450
#define ATOM_FDIM 35
#define IN_FDIM 40        // ATOM_FDIM + BOND_FDIM
#define MAX_NB 15
#define N_ATOMS 30000
#define N_BONDS 60000
#define N_MESS 10001
#define N_MOLS 1000
#define DEPTH 4
#define NTOT (N_MESS + N_BONDS)

#define KPAD 512          // padded K for concat GEMMs; also message-row stride
#define MB_PAD 60032      // N_BONDS padded to x128
#define MA_PAD 30080      // N_ATOMS padded to x128

typedef _Float16 f16x8_t __attribute__((ext_vector_type(8)));
typedef float f32x4_t __attribute__((ext_vector_type(4)));
typedef unsigned short ushort8_t __attribute__((ext_vector_type(8)));

// ---- helpers ---------------------------------------------------------------
__device__ __forceinline__ float h2f(unsigned short u) {
    return (float)__builtin_bit_cast(_Float16, u);
}
__device__ __forceinline__ unsigned short f2h(float f) {
    return __builtin_bit_cast(unsigned short, (_Float16)f);   // RNE v_cvt_f16_f32
}
__device__ __forceinline__ void st_out(unsigned short* p, float v) { *p = f2h(v); }
__device__ __forceinline__ void st_out(float* p, float v) { *p = v; }

__device__ __forceinline__ void g2l16(const unsigned short* g, unsigned short* l) {
    __builtin_amdgcn_global_load_lds(
        (const __attribute__((address_space(1))) void*)g,
        (__attribute__((address_space(3))) void*)l, 16, 0, 0);
}

// int64-vs-int32 sniff: int64 index arrays have zero high words
__device__ __forceinline__ bool sniff_is64(const void* g) {
    const int* g32 = (const int*)g;
    return (g32[1] | g32[3] | g32[5] | g32[7]) == 0;
}
__device__ __forceinline__ long long load_idx(const void* g, size_t pos, bool is64) {
    return is64 ? ((const long long*)g)[pos] : (long long)((const int*)g)[pos];
}

// ---- prep kernels ----------------------------------------------------------
__global__ void zero_stats_kernel(float* __restrict__ p) {
    int i = blockIdx.x * blockDim.x + threadIdx.x;
    if (i < 2 * HIDDEN) p[i] = 0.f;
}

// Wih[512][512]: rows<450: cols 0..39 = W_i, 40..489 = W_h, else 0
__global__ void build_wih_kernel(const float* __restrict__ W_i,
                                 const float* __restrict__ W_h,
                                 unsigned short* __restrict__ Wih) {
    int t = blockIdx.x * blockDim.x + threadIdx.x;
    if (t >= KPAD * KPAD) return;
    int n = t >> 9, k = t & 511;
    float v = 0.f;
    if (n < HIDDEN) {
        if (k < IN_FDIM)            v = W_i[(size_t)n * IN_FDIM + k];
        else if (k < IN_FDIM + HIDDEN) v = W_h[(size_t)n * HIDDEN + (k - IN_FDIM)];
    }
    Wih[t] = f2h(v);
}

// Wo[512][512]: rows<450: cols 0..34 = W_o[:,0:35], 40..489 = W_o[:,35:485]
__global__ void build_wo_kernel(const float* __restrict__ W_o,
                                unsigned short* __restrict__ Wo) {
    int t = blockIdx.x * blockDim.x + threadIdx.x;
    if (t >= KPAD * KPAD) return;
    int n = t >> 9, k = t & 511;
    float v = 0.f;
    if (n < HIDDEN) {
        if (k < ATOM_FDIM)                   v = W_o[(size_t)n * (ATOM_FDIM + HIDDEN) + k];
        else if (k >= IN_FDIM && k < IN_FDIM + HIDDEN)
            v = W_o[(size_t)n * (ATOM_FDIM + HIDDEN) + ATOM_FDIM + (k - IN_FDIM)];
    }
    Wo[t] = f2h(v);
}

// Abond: write only live cols: 0..63 (fbonds + it0 zeros) and 496..511 (pad)
// 10 vec8 chunks per row; gather rewrites cols 40..495 every iteration.
__global__ void cvt_fbonds_kernel(const float* __restrict__ fbonds,
                                  unsigned short* __restrict__ Ab) {
    int t = blockIdx.x * blockDim.x + threadIdx.x;
    if (t >= MB_PAD * 10) return;
    int r = t / 10, c = t % 10;
    int col0 = (c < 8) ? c * 8 : 496 + (c - 8) * 8;
    ushort8_t o;
    #pragma unroll
    for (int j = 0; j < 8; ++j) {
        int cc = col0 + j;
        float v = (r < N_BONDS && cc < IN_FDIM) ? fbonds[(size_t)r * IN_FDIM + cc] : 0.f;
        o[j] = f2h(v);
    }
    *(ushort8_t*)(Ab + (size_t)r * KPAD + col0) = o;
}

// Aatom: live cols 0..39 (fatoms+pad) and 496..511: 7 vec8 chunks per row
__global__ void cvt_fatoms_kernel(const float* __restrict__ fatoms,
                                  unsigned short* __restrict__ Aa) {
    int t = blockIdx.x * blockDim.x + threadIdx.x;
    if (t >= MA_PAD * 7) return;
    int r = t / 7, c = t % 7;
    int col0 = (c < 5) ? c * 8 : 496 + (c - 5) * 8;
    ushort8_t o;
    #pragma unroll
    for (int j = 0; j < 8; ++j) {
        int cc = col0 + j;
        float v = (r < N_ATOMS && cc < ATOM_FDIM) ? fatoms[(size_t)r * ATOM_FDIM + cc] : 0.f;
        o[j] = f2h(v);
    }
    *(ushort8_t*)(Aa + (size_t)r * KPAD + col0) = o;
}

// tree_f16[10001][512]: cols<450 from fp32 tree, else 0
__global__ void cvt_tree_kernel(const float* __restrict__ tree,
                                unsigned short* __restrict__ tb) {
    int t = blockIdx.x * blockDim.x + threadIdx.x;
    if (t >= N_MESS * 64) return;
    int r = t >> 6, c8 = (t & 63) * 8;
    ushort8_t o;
    #pragma unroll
    for (int j = 0; j < 8; ++j) {
        int c = c8 + j;
        float v = (c < HIDDEN) ? tree[(size_t)r * HIDDEN + c] : 0.f;
        o[j] = f2h(v);
    }
    *(ushort8_t*)(tb + (size_t)r * KPAD + c8) = o;
}

// zero gm pad cols 448..511 once (GEMM rewrites 448,449 with real data)
__global__ void zero_gmpad_kernel(unsigned short* __restrict__ gm) {
    int t = blockIdx.x * blockDim.x + threadIdx.x;
    if (t >= N_BONDS * 8) return;
    int r = t >> 3, c = 448 + (t & 7) * 8;
    ushort8_t z = {0, 0, 0, 0, 0, 0, 0, 0};
    *(ushort8_t*)(gm + (size_t)r * KPAD + c) = z;
}

// ---- MFMA GEMM: Out = act(A @ B^T [+bias]) ---------------------------------
// A [Mpad][512] f16 row-major, B [512][512] f16 row-major (rows >=450 zero).
// 128x128 tile, BK=32, 4 waves (2x2), each wave 4x4 frags of 16x16x32.
// 1D grid with XCD-pair swizzle: blocks g, g+8, g+16, g+24 = the 4 n-tiles of
// one m-tile, all on the same XCD (g%8) -> A m-slice fetched ~once per GEMM.
template<bool RELU, bool BIAS, typename OT>
__global__ __launch_bounds__(256)
void mfma_gemm_kernel(const unsigned short* __restrict__ A,
                      const unsigned short* __restrict__ B,
                      const float* __restrict__ bias,
                      OT* __restrict__ Out, int ldo,
                      int M, int Nvalid, int K, int mtiles)
{
    __shared__ unsigned short As[128 * 32];
    __shared__ unsigned short Bs[128 * 32];
    const int g = blockIdx.x;
    const int mt = (g >> 5) * 8 + (g & 7);
    const int nt = (g >> 3) & 3;
    if (mt >= mtiles) return;
    const int m0 = mt * 128, n0 = nt * 128;

    const int tid  = threadIdx.x;
    const int wave = tid >> 6, lane = tid & 63;
    const int wm = wave >> 1, wn = wave & 1;

    const unsigned short* At = A + (size_t)m0 * KPAD;
    const unsigned short* Bt = B + (size_t)n0 * KPAD;

    // staging: chunk c covers LDS bytes [c*16, c*16+16) = row c>>2, k8 (c&3)*8
    const int c0 = wave * 128 + lane;
    const int c1 = c0 + 64;
    const int rA0 = c0 >> 2, kc0 = (c0 & 3) * 8;
    const int rA1 = c1 >> 2, kc1 = (c1 & 3) * 8;
    unsigned short* lA0 = &As[(size_t)(wave * 128) * 8];
    unsigned short* lA1 = &As[(size_t)(wave * 128 + 64) * 8];
    unsigned short* lB0 = &Bs[(size_t)(wave * 128) * 8];
    unsigned short* lB1 = &Bs[(size_t)(wave * 128 + 64) * 8];

    const int fr = lane & 15, kof = (lane >> 4) * 8;

    f32x4_t acc[4][4];
    #pragma unroll
    for (int mi = 0; mi < 4; ++mi)
        #pragma unroll
        for (int ni = 0; ni < 4; ++ni)
            acc[mi][ni] = f32x4_t{0.f, 0.f, 0.f, 0.f};

    for (int k0 = 0; k0 < K; k0 += 32) {
        g2l16(At + (size_t)rA0 * KPAD + k0 + kc0, lA0);
        g2l16(At + (size_t)rA1 * KPAD + k0 + kc1, lA1);
        g2l16(Bt + (size_t)rA0 * KPAD + k0 + kc0, lB0);
        g2l16(Bt + (size_t)rA1 * KPAD + k0 + kc1, lB1);
        __syncthreads();

        f16x8_t a[4], b[4];
        #pragma unroll
        for (int mi = 0; mi < 4; ++mi)
            a[mi] = __builtin_bit_cast(f16x8_t,
                *(const ushort8_t*)&As[(size_t)((wm * 64 + mi * 16 + fr) * 32 + kof)]);
        #pragma unroll
        for (int ni = 0; ni < 4; ++ni)
            b[ni] = __builtin_bit_cast(f16x8_t,
                *(const ushort8_t*)&Bs[(size_t)((wn * 64 + ni * 16 + fr) * 32 + kof)]);
        #pragma unroll
        for (int mi = 0; mi < 4; ++mi)
            #pragma unroll
            for (int ni = 0; ni < 4; ++ni)
                acc[mi][ni] = __builtin_amdgcn_mfma_f32_16x16x32_f16(
                    a[mi], b[ni], acc[mi][ni], 0, 0, 0);
        __syncthreads();
    }

    // epilogue: C/D layout col=lane&15, row=(lane>>4)*4+reg  [m89/m91]
    #pragma unroll
    for (int mi = 0; mi < 4; ++mi) {
        int row_b = m0 + wm * 64 + mi * 16 + (lane >> 4) * 4;
        #pragma unroll
        for (int ni = 0; ni < 4; ++ni) {
            int col = n0 + wn * 64 + ni * 16 + fr;
            if (col >= Nvalid) continue;
            float bi = BIAS ? bias[col] : 0.f;
            #pragma unroll
            for (int r = 0; r < 4; ++r) {
                int row = row_b + r;
                if (row >= M) continue;
                float v = acc[mi][ni][r] + bi;
                if (RELU) v = fmaxf(v, 0.f);
                st_out(&Out[(size_t)row * ldo + col], v);
            }
        }
    }
}

// ---- gather-sum (f16 tables, ld=512) -> Adst cols [40,496) (ld=512) --------
// One wave per output row; 15 wave-uniform row pointers via readfirstlane;
// rows are 1024B = 64 lanes x 16B, 128B-line aligned.
__global__ __launch_bounds__(256)
void gather_kernel(const void* __restrict__ graph, int n_rows,
                   const unsigned short* __restrict__ tree,
                   const unsigned short* __restrict__ gm,
                   unsigned short* __restrict__ Adst)
{
    const bool is64 = sniff_is64(graph);
    int w    = (int)((blockIdx.x * 256 + threadIdx.x) >> 6);
    int lane = threadIdx.x & 63;
    if (w >= n_rows) return;
    const size_t coff = (size_t)lane * 8;

    const unsigned short* rp[MAX_NB];
    #pragma unroll
    for (int nb = 0; nb < MAX_NB; ++nb) {
        long long idx = load_idx(graph, (size_t)w * MAX_NB + nb, is64);
        if (idx < 0) idx = 0;
        if (idx >= NTOT) idx = NTOT - 1;
        int i32 = __builtin_amdgcn_readfirstlane((int)idx);
        rp[nb] = (i32 < N_MESS) ? tree + (size_t)i32 * KPAD
                                : gm + (size_t)(i32 - N_MESS) * KPAD;
    }
    ushort8_t v[MAX_NB];
    #pragma unroll
    for (int nb = 0; nb < MAX_NB; ++nb)
        v[nb] = *(const ushort8_t*)(rp[nb] + coff);

    float acc[8] = {};
    #pragma unroll
    for (int nb = 0; nb < MAX_NB; ++nb)
        #pragma unroll
        for (int j = 0; j < 8; ++j)
            acc[j] += h2f(v[nb][j]);

    if (lane < 57) {   // 57*8 = 456 cols -> Adst cols 40..495
        ushort8_t o;
        #pragma unroll
        for (int j = 0; j < 8; ++j) o[j] = f2h(acc[j]);
        *(ushort8_t*)(Adst + (size_t)w * KPAD + IN_FDIM + coff) = o;
    }
}

// ---- column stats over h[30000][450] f16 -----------------------------------
__global__ __launch_bounds__(256)
void colstats_kernel(const unsigned short* __restrict__ h,
                     float* __restrict__ sums, float* __restrict__ sumsq)
{
    int t = threadIdx.x;
    int r0 = blockIdx.x * 250;
    float s0 = 0.f, q0 = 0.f, s1 = 0.f, q1 = 0.f;
    bool has1 = t < HIDDEN - 256;
    for (int r = r0; r < r0 + 250; ++r) {
        const unsigned short* row = h + (size_t)r * HIDDEN;
        float v0 = h2f(row[t]);
        s0 += v0; q0 += v0 * v0;
        if (has1) {
            float v1 = h2f(row[t + 256]);
            s1 += v1; q1 += v1 * v1;
        }
    }
    atomicAdd(&sums[t], s0);
    atomicAdd(&sumsq[t], q0);
    if (has1) {
        atomicAdd(&sums[t + 256], s1);
        atomicAdd(&sumsq[t + 256], q1);
    }
}

__global__ void finalize_stats_kernel(const float* __restrict__ sums,
                                      const float* __restrict__ sumsq,
                                      const float* __restrict__ gamma,
                                      const float* __restrict__ beta,
                                      float* __restrict__ scale,
                                      float* __restrict__ shift)
{
    int c = blockIdx.x * blockDim.x + threadIdx.x;
    if (c >= HIDDEN) return;
    float mean = sums[c] * (1.f / N_ATOMS);
    float var  = sumsq[c] * (1.f / N_ATOMS) - mean * mean;
    float inv  = rsqrtf(var + 1e-5f);
    float sc   = gamma[c] * inv;
    scale[c] = sc;
    shift[c] = beta[c] - mean * sc;
}

// ---- per-mol mean of relu(h*scale + shift), h f16 --------------------------
__global__ __launch_bounds__(256)
void pool_kernel(const unsigned short* __restrict__ h, const void* __restrict__ scope,
                 const float* __restrict__ scale, const float* __restrict__ shift,
                 float* __restrict__ out)
{
    int m = blockIdx.x;
    const int* s32 = (const int*)scope;
    bool is64 = (s32[1] == 0 && s32[3] == 0);
    long long start, len, nxt;
    if (is64) {
        const long long* s = (const long long*)scope;
        start = s[2 * m]; len = s[2 * m + 1];
        nxt = (m < N_MOLS - 1) ? s[2 * m + 2] : (long long)N_ATOMS;
    } else {
        start = s32[2 * m]; len = s32[2 * m + 1];
        nxt = (m < N_MOLS - 1) ? (long long)s32[2 * m + 2] : (long long)N_ATOMS;
    }
    if (start < 0) start = 0;
    if (nxt > N_ATOMS) nxt = N_ATOMS;

    int t = threadIdx.x;
    bool has1 = t < HIDDEN - 256;
    float sc0 = scale[t], sh0 = shift[t];
    float sc1 = 0.f, sh1 = 0.f;
    if (has1) { sc1 = scale[t + 256]; sh1 = shift[t + 256]; }
    float a0 = 0.f, a1 = 0.f;
    for (long long r = start; r < nxt; ++r) {
        const unsigned short* row = h + (size_t)r * HIDDEN;
        a0 += fmaxf(fmaf(h2f(row[t]), sc0, sh0), 0.f);
        if (has1) a1 += fmaxf(fmaf(h2f(row[t + 256]), sc1, sh1), 0.f);
    }
    float den = (float)(len > 0 ? len : 1);
    out[(size_t)m * HIDDEN + t] = (len > 0) ? a0 / den : 0.f;
    if (has1) out[(size_t)m * HIDDEN + t + 256] = (len > 0) ? a1 / den : 0.f;
}

// ---------------------------------------------------------------------------
extern "C" void kernel_launch(void* const* d_in, const int* in_sizes, int n_in,
                              void* d_out, int out_size, void* d_ws, size_t ws_size,
                              hipStream_t stream)
{
    const float* fatoms = (const float*)d_in[0];
    const float* fbonds = (const float*)d_in[1];
    const void*  agraph = d_in[2];
    const void*  bgraph = d_in[3];
    const void*  scope  = d_in[4];
    const float* tree   = (const float*)d_in[5];
    const float* W_i    = (const float*)d_in[6];
    const float* W_h    = (const float*)d_in[7];
    const float* W_o    = (const float*)d_in[8];
    const float* b_o    = (const float*)d_in[9];
    const float* gamma  = (const float*)d_in[10];
    const float* beta   = (const float*)d_in[11];
    float* out = (float*)d_out;

    // ---- workspace layout (all offsets 256B aligned) ----
    char* ws = (char*)d_ws;
    size_t off = 0;
    auto alloc = [&](size_t bytes) { char* p = ws + off; off += (bytes + 255) & ~(size_t)255; return p; };
    float*          sums  = (float*)alloc(4 * HIDDEN * sizeof(float));
    float*          sumsq = sums + HIDDEN;
    float*          scale = sums + 2 * HIDDEN;
    float*          shift = sums + 3 * HIDDEN;
    unsigned short* Abond = (unsigned short*)alloc((size_t)MB_PAD * KPAD * 2);
    unsigned short* Aatom = (unsigned short*)alloc((size_t)MA_PAD * KPAD * 2);
    unsigned short* gm    = (unsigned short*)alloc((size_t)N_BONDS * KPAD * 2);
    unsigned short* tb    = (unsigned short*)alloc((size_t)N_MESS * KPAD * 2);
    unsigned short* Wih   = (unsigned short*)alloc((size_t)KPAD * KPAD * 2);
    unsigned short* Wo    = (unsigned short*)alloc((size_t)KPAD * KPAD * 2);
    unsigned short* h     = (unsigned short*)alloc((size_t)N_ATOMS * HIDDEN * 2);
    (void)ws_size;

    dim3 blk(256);

    // ---- prep ----
    zero_stats_kernel<<<4, blk, 0, stream>>>(sums);
    build_wih_kernel<<<(KPAD * KPAD + 255) / 256, blk, 0, stream>>>(W_i, W_h, Wih);
    build_wo_kernel<<<(KPAD * KPAD + 255) / 256, blk, 0, stream>>>(W_o, Wo);
    cvt_fbonds_kernel<<<(MB_PAD * 10 + 255) / 256, blk, 0, stream>>>(fbonds, Abond);
    cvt_fatoms_kernel<<<(MA_PAD * 7 + 255) / 256, blk, 0, stream>>>(fatoms, Aatom);
    cvt_tree_kernel<<<(N_MESS * 64 + 255) / 256, blk, 0, stream>>>(tree, tb);
    zero_gmpad_kernel<<<(N_BONDS * 8 + 255) / 256, blk, 0, stream>>>(gm);

    // 1D swizzled grids: bond 469 m-tiles -> 59*32 blocks; atom 235 -> 30*32
    dim3 gBond(59 * 32);
    dim3 gAtom(30 * 32);

    // it0: gm = relu(fbonds @ W_i^T)   (nei cols of Abond are zero -> K=64)
    mfma_gemm_kernel<true, false, unsigned short><<<gBond, blk, 0, stream>>>(
        Abond, Wih, nullptr, gm, KPAD, N_BONDS, HIDDEN, 64, 469);

    // it1..3: nei = gather(bgraph); gm = relu([fbonds|nei] @ [W_i|W_h]^T)
    for (int it = 0; it < DEPTH - 1; ++it) {
        gather_kernel<<<N_BONDS / 4, blk, 0, stream>>>(bgraph, N_BONDS, tb, gm, Abond);
        mfma_gemm_kernel<true, false, unsigned short><<<gBond, blk, 0, stream>>>(
            Abond, Wih, nullptr, gm, KPAD, N_BONDS, HIDDEN, KPAD, 469);
    }

    // atom side: nei = gather(agraph); h = [fatoms|nei] @ W_o^T + b_o (f16)
    gather_kernel<<<N_ATOMS / 4, blk, 0, stream>>>(agraph, N_ATOMS, tb, gm, Aatom);
    mfma_gemm_kernel<false, true, unsigned short><<<gAtom, blk, 0, stream>>>(
        Aatom, Wo, b_o, h, HIDDEN, N_ATOMS, HIDDEN, KPAD, 235);

    // layernorm stats + pool
    colstats_kernel<<<120, blk, 0, stream>>>(h, sums, sumsq);
    finalize_stats_kernel<<<1, 512, 0, stream>>>(sums, sumsq, gamma, beta, scale, shift);
    pool_kernel<<<N_MOLS, blk, 0, stream>>>(h, scope, scale, shift, out);
}